// Round 9
// baseline (649.931 us; speedup 1.0000x reference)
//
#include <hip/hip_runtime.h>
#include <stdint.h>

// ============================================================================
// SubspaceRankHopLayer on MI355X (gfx950)
//
// R6: wave-register chol. 628. R7: reg-staged k_gg 165, no Lbf. 657.
// R9/R10: swizzle (conflicts 13.3M->3.15M, ~neutral); spill lesson (256,3).
// R11: split k_big(512thr)/k_grad, T2w stride fix. 649, absmax 0.03125.
//   Little's-law diagnosis: 48 loads x 16B per barrier interval = 768B/block
//   in flight; need ~8.6KB/CU for 6 TB/s -> the per-tile vmcnt(0) drain caps
//   k_big at ~1.1 TB/s REGARDLESS of occupancy. Structural fix = T3/T4.
// R12 (this round):
//   - k_big: depth-2 pipeline, 3 LDS buffers (149,760B, 1 blk/CU, 8 waves):
//     per tile issue A-regs+B-DMA for t+2, MFMA buf[t%3], vmcnt(4) (B(t+2)
//     SPANS the barrier), cvt+write A, lgkmcnt(0), raw s_barrier. 4 B-loads/
//     thread always in flight = 32KB/CU outstanding.
//   - k_gpart fused into k_zgemm (Z tile already in LDS; partial Gram ->
//     Gp[5][64][64][64]; k_gred sums 64 chunks). -1 launch, -5MB re-read.
// Predict: k_big ~60-90us, total ~545-575, absmax 0.03125.
// ============================================================================

typedef __attribute__((ext_vector_type(8))) short  s16x8;   // 8 bf16 (4 VGPR)
typedef __attribute__((ext_vector_type(4))) float  f32x4;

#define NNODE 8192
#define DIN   256
#define KHOP  5
#define SDM   64

// ---------------- ws layout (bytes) ----------------
static const size_t OFF_Q    = 0;                                   // Q f32 [5][256][64]
static const size_t OFF_QT   = OFF_Q   + (size_t)5*256*64*4;        // Qt bf16 [5][64][256]
static const size_t OFF_ZT   = OFF_QT  + (size_t)5*64*256*2;        // Zt bf16 [5][8192][64]
static const size_t OFF_GP   = OFF_ZT  + (size_t)5*8192*64*2;       // Gpart f32 [5][64][64][64]
static const size_t OFF_LM   = OFF_GP  + (size_t)5*64*4096*4;       // Lm f32 [5][64][64]
static const size_t OFF_RD   = OFF_LM  + (size_t)5*4096*4;          // rdiag f32 [5][64]
static const size_t OFF_LU   = OFF_RD  + (size_t)5*64*4;            // Lu f32 [5][64][64]
static const size_t OFF_RDU  = OFF_LU  + (size_t)5*4096*4;          // rdiag_u f32 [5][64]
static const size_t OFF_RE   = OFF_RDU + (size_t)5*64*4;            // rank_eff [5] (pad 64)
static const size_t OFF_W    = OFF_RE  + 64;                        // w [5] (pad 64)
static const size_t OFF_T2   = OFF_W   + 64;                        // T2w bf16 [5][256][64]
static const size_t OFF_HWT  = OFF_T2  + (size_t)5*256*64*2;        // hwT bf16 [256][8192]
static const size_t OFF_WBF  = OFF_HWT + (size_t)256*8192*2;        // W_in bf16 [256][256]
static const size_t OFF_HP   = OFF_WBF + (size_t)256*256*2;         // (unused)
static const size_t OFF_PART = OFF_HP  + (size_t)8192*256*2;        // partial bf16 [9][8192][256]

__device__ __forceinline__ unsigned short f2bf(float f){
  unsigned u = __builtin_bit_cast(unsigned, f);
  u += 0x7FFFu + ((u >> 16) & 1u);            // RNE
  return (unsigned short)(u >> 16);
}
__device__ __forceinline__ float bf2f(unsigned h){
  return __builtin_bit_cast(float, h << 16);
}
__device__ __forceinline__ void gl_lds16(const void* g, void* l){
  __builtin_amdgcn_global_load_lds(
      (const __attribute__((address_space(1))) void*)g,
      (__attribute__((address_space(3))) void*)l, 16, 0, 0);
}
__device__ __forceinline__ f32x4 mfma16(s16x8 a, s16x8 b, f32x4 c){
  return __builtin_amdgcn_mfma_f32_16x16x32_bf16(a, b, c, 0, 0, 0);
}
// swizzled byte offset within a chunk row-block: row7 in [0,8), colbyte in [0,128)
__device__ __forceinline__ int swz(int row7, int colbyte){
  return row7*128 + (colbyte ^ (row7 << 4));
}

// ---------------------------------------------------------------------------
// Wave-register Cholesky of 64x64 SPD. One wave; lane = row; a[64] regs.
// ---------------------------------------------------------------------------
__device__ __forceinline__ void wave_chol64(float* a, float& rdk, int lane){
  rdk = 0.0f;
  #pragma unroll
  for (int j = 0; j < 64; ++j){
    float dj  = __shfl(a[j], j);                 // A[j][j] fully updated
    float d   = sqrtf(fmaxf(dj, 1e-20f));
    float rdj = 1.0f / d;
    float cj  = a[j] * rdj;                      // L[i][j] (i>j); d at i==j
    a[j] = cj;
    if (lane == j) rdk = rdj;
    #pragma unroll
    for (int l = j+1; l < 64; ++l)
      a[l] -= cj * __shfl(cj, l);                // rank-1 update, col l
  }
}

// ---------------------------------------------------------------------------
// K_PRE: 5 blocks: Gram (256 thr) + wave0 register-Cholesky of U_k.
// ---------------------------------------------------------------------------
__global__ __launch_bounds__(256) void k_pre(const float* __restrict__ U,
                                             float* __restrict__ Lu,
                                             float* __restrict__ rdu){
  __shared__ float A[64*65];
  int tid = threadIdx.x;
  int k = blockIdx.x;
  const float* Uk = U + (size_t)k*16384;
  int ti = tid >> 4, tj = tid & 15;
  float s[16];
  #pragma unroll
  for (int i = 0; i < 16; ++i) s[i] = 0.0f;
  for (int n = 0; n < 256; ++n){
    f32x4 xa = *(const f32x4*)(Uk + n*64 + ti*4);
    f32x4 xb = *(const f32x4*)(Uk + n*64 + tj*4);
    #pragma unroll
    for (int p = 0; p < 4; ++p)
      #pragma unroll
      for (int q = 0; q < 4; ++q) s[p*4+q] += xa[p]*xb[q];
  }
  #pragma unroll
  for (int p = 0; p < 4; ++p)
    #pragma unroll
    for (int q = 0; q < 4; ++q) A[(ti*4+p)*65 + tj*4+q] = s[p*4+q];
  __syncthreads();
  if (tid < 64){
    int lane = tid;
    float a[64];
    #pragma unroll
    for (int l = 0; l < 64; ++l) a[l] = A[lane*65 + l];
    float rdk;
    wave_chol64(a, rdk, lane);
    #pragma unroll
    for (int l = 0; l < 64; ++l) Lu[(size_t)k*4096 + lane*64 + l] = a[l];
    rdu[k*64 + lane] = rdk;
  }
}

// ---------------------------------------------------------------------------
// K1b: wave-parallel forward solve L x = u_row -> Q rows. grid(64,5).
// ---------------------------------------------------------------------------
__global__ __launch_bounds__(256) void k_qsolve(const float* __restrict__ U,
                                                const float* __restrict__ Lu,
                                                const float* __restrict__ rdu,
                                                float* __restrict__ Qf,
                                                unsigned short* __restrict__ Qt){
  int k = blockIdx.y, tid = threadIdx.x, wave = tid >> 6, lane = tid & 63;
  __shared__ float Al[64*65];
  __shared__ float rds[64];
  for (int e = tid; e < 4096; e += 256) Al[(e>>6)*65 + (e&63)] = Lu[(size_t)k*4096 + e];
  if (tid < 64) rds[tid] = rdu[k*64 + tid];
  __syncthreads();
  int n = blockIdx.x*4 + wave;
  float x = U[((size_t)k*256 + n)*64 + lane];
  #pragma unroll
  for (int j = 0; j < 64; ++j){
    float zj = __shfl(x, j) * rds[j];
    x = (lane == j) ? zj : (lane > j ? x - Al[lane*65+j]*zj : x);
  }
  Qf[((size_t)k*256 + n)*64 + lane] = x;
  Qt[(size_t)k*16384 + lane*256 + n] = f2bf(x);   // Qt[k][s][d]
}

// ---------------------------------------------------------------------------
// K2: Z_k = hops_k @ Q_k [8192,64] bf16 + fused 128-row partial Gram.
// grid(64,5), BM=128 BN=64 BK=64. Gp[(k*64+bx)] = Z_tile^T Z_tile.
// ---------------------------------------------------------------------------
__global__ __launch_bounds__(256,2) void k_zgemm(const float* __restrict__ hops,
                                                 const unsigned short* __restrict__ Qt,
                                                 unsigned short* __restrict__ Zt,
                                                 float* __restrict__ Gp){
  __shared__ __align__(16) unsigned short Al[128][72];
  __shared__ __align__(16) unsigned short Bl[64][64];
  int tid = threadIdx.x, lane = tid & 63, wave = tid >> 6;
  int q = lane >> 4, r = lane & 15;
  int k = blockIdx.y, m0 = blockIdx.x * 128;
  f32x4 acc[2][4];
  #pragma unroll
  for (int a = 0; a < 2; ++a)
    #pragma unroll
    for (int b = 0; b < 4; ++b) acc[a][b] = (f32x4){0,0,0,0};
  int rr = tid >> 1, half = tid & 1;
  for (int it = 0; it < 4; ++it){
    __syncthreads();
    #pragma unroll
    for (int i = 0; i < 2; ++i){
      int o = i*4096 + wave*1024 + lane*16;
      int srow = o >> 7, kc = (o & 127) >> 1;
      gl_lds16(Qt + (size_t)k*16384 + srow*256 + it*64 + kc,
               (char*)&Bl[0][0] + i*4096 + wave*1024);
    }
    const float* ga = hops + ((size_t)k*NNODE + m0 + rr)*256 + it*64 + half*32;
    f32x4 v[8];
    #pragma unroll
    for (int i = 0; i < 8; ++i) v[i] = *(const f32x4*)(ga + i*4);
    #pragma unroll
    for (int i = 0; i < 4; ++i){
      s16x8 t;
      #pragma unroll
      for (int j = 0; j < 8; ++j){ int e = i*8+j; t[j] = (short)f2bf(v[e>>2][e&3]); }
      *(s16x8*)&Al[rr][half*32 + i*8] = t;
    }
    __syncthreads();
    #pragma unroll
    for (int h = 0; h < 2; ++h){
      int ko = h*32 + q*8;
      s16x8 b[4];
      #pragma unroll
      for (int ni = 0; ni < 4; ++ni) b[ni] = *(const s16x8*)&Bl[ni*16 + r][ko];
      #pragma unroll
      for (int mi = 0; mi < 2; ++mi){
        s16x8 a = *(const s16x8*)&Al[wave*32 + mi*16 + r][ko];
        #pragma unroll
        for (int ni = 0; ni < 4; ++ni) acc[mi][ni] = mfma16(a, b[ni], acc[mi][ni]);
      }
    }
  }
  // epilogue: write Zt (global) + stage Z bf16 into Al (own wave's rows only)
  #pragma unroll
  for (int mi = 0; mi < 2; ++mi)
    #pragma unroll
    for (int ni = 0; ni < 4; ++ni)
      #pragma unroll
      for (int ii = 0; ii < 4; ++ii){
        int ml = wave*32 + mi*16 + q*4 + ii;
        int sc = ni*16 + r;
        unsigned short v = f2bf(acc[mi][ni][ii]);
        Zt[((size_t)k*NNODE + m0 + ml)*64 + sc] = v;
        Al[ml][sc] = v;
      }
  __syncthreads();
  // partial Gram of this 128-row tile (gpart's loop, pitch 72)
  int ti = tid >> 4, tj = tid & 15;
  float g16[16];
  #pragma unroll
  for (int i = 0; i < 16; ++i) g16[i] = 0.0f;
  for (int n = 0; n < 128; ++n){
    const unsigned short* row = &Al[n][0];
    uint2 ua = *(const uint2*)(row + ti*4);
    uint2 ub = *(const uint2*)(row + tj*4);
    float xa[4] = { bf2f(ua.x & 0xffff), bf2f(ua.x >> 16), bf2f(ua.y & 0xffff), bf2f(ua.y >> 16) };
    float xb[4] = { bf2f(ub.x & 0xffff), bf2f(ub.x >> 16), bf2f(ub.y & 0xffff), bf2f(ub.y >> 16) };
    #pragma unroll
    for (int p = 0; p < 4; ++p)
      #pragma unroll
      for (int qn = 0; qn < 4; ++qn) g16[p*4+qn] += xa[p]*xb[qn];
  }
  float* go = Gp + ((size_t)(k*64 + blockIdx.x))*4096;
  #pragma unroll
  for (int p = 0; p < 4; ++p)
    #pragma unroll
    for (int qn = 0; qn < 4; ++qn) go[(ti*4+p)*64 + tj*4+qn] = g16[p*4+qn];
}

// ---------------------------------------------------------------------------
// K4: reduce 64 Gpart chunks -> G; rank_eff; M = I + coeff*G; register-chol.
// ---------------------------------------------------------------------------
__global__ __launch_bounds__(256) void k_gred(const float* __restrict__ Gp,
                                              float* __restrict__ LmO,
                                              float* __restrict__ rdO,
                                              float* __restrict__ reO){
  int k = blockIdx.x, tid = threadIdx.x;
  __shared__ float A[64*65];
  __shared__ float red[256];
  int ti = tid >> 4, tj = tid & 15;
  float s[16];
  #pragma unroll
  for (int i = 0; i < 16; ++i) s[i] = 0.0f;
  for (int c = 0; c < 64; ++c){
    const float* g = Gp + ((size_t)(k*64 + c))*4096 + (ti*4)*64 + tj*4;
    #pragma unroll
    for (int p = 0; p < 4; ++p)
      #pragma unroll
      for (int qn = 0; qn < 4; ++qn) s[p*4+qn] += g[p*64+qn];
  }
  const float sc    = 1.0f / (8192.0f + 1e-8f);
  const float coeff = 64.0f / (8192.0f*0.25f + 1e-8f);
  float trp = 0.0f, tr2p = 0.0f;
  #pragma unroll
  for (int p = 0; p < 4; ++p)
    #pragma unroll
    for (int qn = 0; qn < 4; ++qn){
      float gg = s[p*4+qn];
      float sg = gg * sc;
      tr2p += sg*sg;
      int row = ti*4+p, col = tj*4+qn;
      if (row == col) trp += sg;
      A[row*65 + col] = (row == col ? 1.0f : 0.0f) + coeff*gg;
    }
  red[tid] = trp; __syncthreads();
  for (int o = 128; o > 0; o >>= 1){ if (tid < o) red[tid] += red[tid+o]; __syncthreads(); }
  float tr = red[0]; __syncthreads();
  red[tid] = tr2p; __syncthreads();
  for (int o = 128; o > 0; o >>= 1){ if (tid < o) red[tid] += red[tid+o]; __syncthreads(); }
  float tr2 = red[0];
  if (tid == 0) reO[k] = tr*tr / (tr2 + 1e-8f);
  __syncthreads();
  if (tid < 64){
    int lane = tid;
    float a[64];
    #pragma unroll
    for (int l = 0; l < 64; ++l) a[l] = A[lane*65 + l];
    float rdk;
    wave_chol64(a, rdk, lane);
    #pragma unroll
    for (int l = 0; l < 64; ++l) LmO[(size_t)k*4096 + lane*64 + l] = a[l];
    rdO[k*64 + lane] = rdk;
  }
}

// ---------------------------------------------------------------------------
// K5: tau, softmax over rank_effs -> w; write output tail. 1 block.
// ---------------------------------------------------------------------------
__global__ void k_soft(const float* __restrict__ re, const float* __restrict__ ltau,
                       float* __restrict__ wv, float* __restrict__ dtail){
  if (threadIdx.x == 0){
    float tau = expf(ltau[0]);
    tau = fminf(fmaxf(tau, 0.1f), 10.0f);
    float r[5], m = -1e30f;
    for (int i = 0; i < 5; ++i){ r[i] = re[i]; m = fmaxf(m, r[i]); }
    float e[5], sum = 0.0f;
    for (int i = 0; i < 5; ++i){ e[i] = expf((r[i]-m)/tau); sum += e[i]; }
    for (int i = 0; i < 5; ++i){
      float w = e[i]/sum;
      wv[i] = w; dtail[i] = r[i]; dtail[5+i] = w;
    }
  }
}

// ---------------------------------------------------------------------------
// K_POST: horizontal fusion, 896 blocks:
//   [0,512):   hwT role; [512,832): t2w role; [832,896): wbf role
// ---------------------------------------------------------------------------
__global__ __launch_bounds__(256) void k_post(const float* __restrict__ hops,
                                              const float* __restrict__ wv,
                                              unsigned short* __restrict__ hwT,
                                              const float* __restrict__ Qf,
                                              const float* __restrict__ LmI,
                                              const float* __restrict__ rdI,
                                              unsigned short* __restrict__ T2w,
                                              const float* __restrict__ Win,
                                              unsigned short* __restrict__ Wbf){
  __shared__ float T[64*65];
  __shared__ float rds[64];
  int bid = blockIdx.x, tid = threadIdx.x;
  if (bid < 512){
    // ---- hwT role ----
    int n0 = (bid & 127)*64, d0 = (bid >> 7)*64;
    float wl[5];
    #pragma unroll
    for (int k = 0; k < 5; ++k) wl[k] = -0.15f * wv[k];   // -ETA*LAM_LAP*w_k
    for (int e = tid; e < 1024; e += 256){
      int row = e >> 4, c4 = (e & 15)*4;
      f32x4 acc = (f32x4){0,0,0,0};
      #pragma unroll
      for (int k = 0; k < 5; ++k){
        f32x4 v = *(const f32x4*)(hops + ((size_t)k*NNODE + n0 + row)*256 + d0 + c4);
        acc += v * wl[k];
      }
      T[row*65 + c4+0] = acc[0]; T[row*65 + c4+1] = acc[1];
      T[row*65 + c4+2] = acc[2]; T[row*65 + c4+3] = acc[3];
    }
    __syncthreads();
    for (int e = tid; e < 1024; e += 256){
      int dr = e >> 4, c4 = (e & 15)*4;
      unsigned short h0 = f2bf(T[(c4+0)*65 + dr]);
      unsigned short h1 = f2bf(T[(c4+1)*65 + dr]);
      unsigned short h2 = f2bf(T[(c4+2)*65 + dr]);
      unsigned short h3 = f2bf(T[(c4+3)*65 + dr]);
      uint2 u; u.x = (unsigned)h0 | ((unsigned)h1 << 16); u.y = (unsigned)h2 | ((unsigned)h3 << 16);
      *(uint2*)(hwT + (size_t)(d0+dr)*NNODE + n0 + c4) = u;
    }
  } else if (bid < 832){
    // ---- t2w role ----
    int i = bid - 512;
    int k = i >> 6, xb = i & 63;
    int wave = tid >> 6, lane = tid & 63;
    for (int e = tid; e < 4096; e += 256) T[(e>>6)*65 + (e&63)] = LmI[(size_t)k*4096 + e];
    if (tid < 64) rds[tid] = rdI[k*64 + tid];
    __syncthreads();
    int n = xb*4 + wave;
    float x = Qf[((size_t)k*256 + n)*64 + lane];
    #pragma unroll
    for (int j = 0; j < 64; ++j){                 // forward: L z = q
      float zj = __shfl(x, j) * rds[j];
      x = (lane == j) ? zj : (lane > j ? x - T[lane*65+j]*zj : x);
    }
    #pragma unroll
    for (int j = 63; j >= 0; --j){                // backward: L^T y = z
      float yj = __shfl(x, j) * rds[j];
      x = (lane == j) ? yj : (lane < j ? x - T[j*65+lane]*yj : x);
    }
    float scale = 0.5f * wv[k];                   // ETA * w_k
    T2w[((size_t)k*256 + n)*64 + lane] = f2bf(scale * x);
  } else {
    // ---- wbf role ----
    int i = bid - 832;
    int e = (i*256 + tid)*4;
    f32x4 v = *(const f32x4*)(Win + e);
    uint2 u;
    u.x = (unsigned)f2bf(v[0]) | ((unsigned)f2bf(v[1]) << 16);
    u.y = (unsigned)f2bf(v[2]) | ((unsigned)f2bf(v[3]) << 16);
    *(uint2*)(Wbf + e) = u;
  }
}

// ---------------------------------------------------------------------------
// K_GRAD: gradgemm standalone. 256 blocks x 256 thr, 36,864 B LDS.
// Zstack[8192,320] @ T2w-stack[320,256] -> slab 8. Both-sides XOR swizzle.
// ---------------------------------------------------------------------------
__global__ __launch_bounds__(256,2) void k_grad(const unsigned short* __restrict__ Zt,
                                                const unsigned short* __restrict__ T2w,
                                                unsigned short* __restrict__ out8){
  __shared__ __align__(16) unsigned short SM[18432];   // 36,864 B
  char* Al = (char*)SM;               // 4 chunks x 1024 B (32 rows x 64)
  char* Bl = (char*)SM + 4096;        // 32 chunks x 1024 B (256 rows x 64)
  int tid = threadIdx.x, lane = tid & 63, wave = tid >> 6;
  int q = lane >> 4, r = lane & 15;
  int m0 = blockIdx.x * 32;
  int gr8 = lane >> 3;                        // row-in-chunk
  int gcS = ((lane & 7) ^ gr8) * 16;          // pre-swizzled src byte col
  f32x4 acc[2][4];
  #pragma unroll
  for (int a = 0; a < 2; ++a)
    #pragma unroll
    for (int b = 0; b < 4; ++b) acc[a][b] = (f32x4){0,0,0,0};
  for (int kk = 0; kk < 5; ++kk){
    __syncthreads();
    {
      int grow = wave*8 + gr8;                // A chunk = wave
      gl_lds16((const char*)Zt + ((size_t)kk*NNODE + m0 + grow)*128 + gcS,
               Al + wave*1024);
    }
    #pragma unroll
    for (int i = 0; i < 8; ++i){
      int cb = i*4 + wave;                    // chunk 0..31
      int grow = cb*8 + gr8;
      gl_lds16((const char*)T2w + (size_t)kk*32768 + (size_t)grow*128 + gcS,
               Bl + cb*1024);
    }
    __syncthreads();
    #pragma unroll
    for (int h = 0; h < 2; ++h){
      int kb = h*64 + q*16;   // byte col
      s16x8 b[4];
      #pragma unroll
      for (int ni = 0; ni < 4; ++ni){
        int row = wave*64 + ni*16 + r;
        b[ni] = *(const s16x8*)(Bl + (row>>3)*1024 + swz(row&7, kb));
      }
      #pragma unroll
      for (int mi = 0; mi < 2; ++mi){
        int row = mi*16 + r;
        s16x8 a = *(const s16x8*)(Al + (row>>3)*1024 + swz(row&7, kb));
        #pragma unroll
        for (int ni = 0; ni < 4; ++ni) acc[mi][ni] = mfma16(a, b[ni], acc[mi][ni]);
      }
    }
  }
  #pragma unroll
  for (int mi = 0; mi < 2; ++mi)
    #pragma unroll
    for (int ni = 0; ni < 4; ++ni)
      #pragma unroll
      for (int ii = 0; ii < 4; ++ii){
        int m = m0 + mi*16 + q*4 + ii;
        int n = wave*64 + ni*16 + r;
        out8[(size_t)m*256 + n] = f2bf(acc[mi][ni][ii]);
      }
}

// ---------------------------------------------------------------------------
// K_BIG: 512 blocks x 512 thr (8 waves), 1 block/CU. Depth-2 counted-vmcnt
// pipeline, 3 LDS buffers (3 x 48 chunks x 1040 B = 149,760 B).
// Per tile t: issue A-regs + B-DMA for t+2 -> buf[(t+2)%3]; MFMA buf[t%3];
// vmcnt(4) (retires B(t+1)+A(t+2); B(t+2) spans the barrier); cvt+write A;
// lgkmcnt(0); raw s_barrier. 4 B-loads/thread always in flight (32 KB/CU).
// ---------------------------------------------------------------------------
__global__ __launch_bounds__(512,2) void k_big(const float* __restrict__ Lf,
                                               const unsigned short* __restrict__ Bt,
                                               unsigned short* __restrict__ part){
  __shared__ __align__(16) unsigned short SM[74880];   // 149,760 B = 3 bufs
  char* SMb = (char*)SM;
  const int CH48 = 48*1040;            // one buffer (16 A + 32 B chunks)
  const int BOFF = 16*1040;            // B region offset within a buffer
  int tid = threadIdx.x, lane = tid & 63, wave = tid >> 6;   // 8 waves
  int q = lane >> 4, r = lane & 15;
  int wr = wave >> 2, wc = wave & 3;
  int m0 = (blockIdx.x & 63) * 128;
  int by = blockIdx.x >> 6;
  size_t kbase = (size_t)by * 1024;
  int sr = lane >> 3;                       // row-in-chunk
  int scS  = ((lane & 7) ^ sr) * 8;         // B: pre-swizzled global col (shorts)
  int sc8a = (lane & 7) * 8;                // A: global col (f32 elems)
  int adst = swz(sr, (lane & 7) * 16);      // A: swizzled dest byte in chunk
  f32x4 acc[4][4];
  #pragma unroll
  for (int a = 0; a < 4; ++a)
    #pragma unroll
    for (int b = 0; b < 4; ++b) acc[a][b] = (f32x4){0,0,0,0};
  f32x4 av[2][2];
  // ---- prologue: stage tiles 0 and 1 ----
  {
    f32x4 av0[2][2];
    #pragma unroll
    for (int i = 0; i < 2; ++i){               // A0 regs (4 loads)
      int c = wave*2 + i;
      const float* p = Lf + (size_t)(m0 + c*8 + sr)*NNODE + kbase + sc8a;
      av0[i][0] = *(const f32x4*)p;
      av0[i][1] = *(const f32x4*)(p + 4);
    }
    #pragma unroll
    for (int i = 0; i < 4; ++i){               // B0 dma (4)
      int cb = wave*4 + i;
      gl_lds16(Bt + (size_t)(cb*8 + sr)*NNODE + kbase + scS,
               SMb + 0*CH48 + BOFF + cb*1040);
    }
    #pragma unroll
    for (int i = 0; i < 2; ++i){               // A1 regs (4)
      int c = wave*2 + i;
      const float* p = Lf + (size_t)(m0 + c*8 + sr)*NNODE + (kbase + 64) + sc8a;
      av[i][0] = *(const f32x4*)p;
      av[i][1] = *(const f32x4*)(p + 4);
    }
    #pragma unroll
    for (int i = 0; i < 4; ++i){               // B1 dma (4)
      int cb = wave*4 + i;
      gl_lds16(Bt + (size_t)(cb*8 + sr)*NNODE + (kbase + 64) + scS,
               SMb + 1*CH48 + BOFF + cb*1040);
    }
    // A0 done after 12 remain (B0,A1,B1)
    asm volatile("s_waitcnt vmcnt(12)" ::: "memory");
    __builtin_amdgcn_sched_barrier(0);
    #pragma unroll
    for (int i = 0; i < 2; ++i){
      int c = wave*2 + i;
      s16x8 t;
      #pragma unroll
      for (int e = 0; e < 8; ++e) t[e] = (short)f2bf(av0[i][e>>2][e&3]);
      *(s16x8*)(SMb + 0*CH48 + c*1040 + adst) = t;
    }
    // B0 + A1 done after 4 remain (B1)
    asm volatile("s_waitcnt vmcnt(4)" ::: "memory");
    __builtin_amdgcn_sched_barrier(0);
    #pragma unroll
    for (int i = 0; i < 2; ++i){
      int c = wave*2 + i;
      s16x8 t;
      #pragma unroll
      for (int e = 0; e < 8; ++e) t[e] = (short)f2bf(av[i][e>>2][e&3]);
      *(s16x8*)(SMb + 1*CH48 + c*1040 + adst) = t;
    }
    asm volatile("s_waitcnt lgkmcnt(0)" ::: "memory");
    __builtin_amdgcn_sched_barrier(0);
    __builtin_amdgcn_s_barrier();
  }
  // ---- main loop ----
  for (int t = 0; t < 16; ++t){
    char* cbuf = SMb + (t % 3)*CH48;
    char* nbuf = SMb + ((t + 2) % 3)*CH48;
    if (t < 14){
      size_t k2 = kbase + (size_t)(t+2)*64;
      #pragma unroll
      for (int i = 0; i < 2; ++i){             // A(t+2) regs
        int c = wave*2 + i;
        const float* p = Lf + (size_t)(m0 + c*8 + sr)*NNODE + k2 + sc8a;
        av[i][0] = *(const f32x4*)p;
        av[i][1] = *(const f32x4*)(p + 4);
      }
      #pragma unroll
      for (int i = 0; i < 4; ++i){             // B(t+2) dma
        int cb = wave*4 + i;
        gl_lds16(Bt + (size_t)(cb*8 + sr)*NNODE + k2 + scS,
                 nbuf + BOFF + cb*1040);
      }
    }
    // MFMA from cbuf (swizzled fragment reads)
    #pragma unroll
    for (int h = 0; h < 2; ++h){
      int kb = h*64 + q*16;   // byte col
      s16x8 b[4];
      #pragma unroll
      for (int ni = 0; ni < 4; ++ni){
        int d = wc*64 + ni*16 + r;
        b[ni] = *(const s16x8*)(cbuf + BOFF + (d>>3)*1040 + swz(d&7, kb));
      }
      #pragma unroll
      for (int mi = 0; mi < 4; ++mi){
        int m = wr*64 + mi*16 + r;
        s16x8 a = *(const s16x8*)(cbuf + (m>>3)*1040 + swz(m&7, kb));
        #pragma unroll
        for (int ni = 0; ni < 4; ++ni) acc[mi][ni] = mfma16(a, b[ni], acc[mi][ni]);
      }
    }
    if (t < 14){
      // retires B(t+1) (4) + A(t+2) (4); leaves B(t+2) (4) in flight
      asm volatile("s_waitcnt vmcnt(4)" ::: "memory");
      __builtin_amdgcn_sched_barrier(0);
      #pragma unroll
      for (int i = 0; i < 2; ++i){
        int c = wave*2 + i;
        s16x8 tt;
        #pragma unroll
        for (int e = 0; e < 8; ++e) tt[e] = (short)f2bf(av[i][e>>2][e&3]);
        *(s16x8*)(nbuf + c*1040 + adst) = tt;
      }
      asm volatile("s_waitcnt lgkmcnt(0)" ::: "memory");
      __builtin_amdgcn_sched_barrier(0);
    } else if (t == 14){
      // drain B(15) before its consumption at t=15
      asm volatile("s_waitcnt vmcnt(0) lgkmcnt(0)" ::: "memory");
      __builtin_amdgcn_sched_barrier(0);
    }
    if (t < 15) __builtin_amdgcn_s_barrier();
  }
  unsigned short* o = part + (size_t)by * 2097152;
  #pragma unroll
  for (int mi = 0; mi < 4; ++mi)
    #pragma unroll
    for (int ni = 0; ni < 4; ++ni)
      #pragma unroll
      for (int ii = 0; ii < 4; ++ii){
        int m = m0 + wr*64 + mi*16 + q*4 + ii;
        int n = wc*64 + ni*16 + r;
        o[(size_t)m*256 + n] = f2bf(acc[mi][ni][ii]);
      }
}

// ---------------------------------------------------------------------------
// K_FINLN: fused combine + GEMM + LayerNorm. grid(128), BM=64 BN=256 K=256.
// ---------------------------------------------------------------------------
__global__ __launch_bounds__(256,2) void k_finln(const float* __restrict__ H,
                                                 const unsigned short* __restrict__ part,
                                                 const unsigned short* __restrict__ Wbf,
                                                 const float* __restrict__ gamma,
                                                 const float* __restrict__ beta,
                                                 float* __restrict__ out){
  __shared__ __align__(16) unsigned short Hl[64][264];   // padded: +4 banks/row
  __shared__ __align__(16) unsigned short Bl[256][64];
  __shared__ float SmR[64][4];
  __shared__ float SqR[64][4];
  int tid = threadIdx.x, lane = tid & 63, wave = tid >> 6;
  int q = lane >> 4, r = lane & 15;
  int m0 = blockIdx.x * 64;
  // ---- phase 1: build Hprox tile ----
  #define PROX(a) ({ float _t = fabsf(a) - 0.025f; _t > 0.0f ? copysignf(_t,(a)) : 0.0f; })
  for (int g = tid; g < 4096; g += 256){
    int row = g >> 6, c4 = (g & 63) * 4;
    size_t e = (size_t)(m0 + row)*256 + c4;
    f32x4 h = *(const f32x4*)(H + e);
    float s0 = h[0], s1 = h[1], s2 = h[2], s3 = h[3];
    #pragma unroll
    for (int sl = 0; sl < 9; ++sl){
      uint2 u = *(const uint2*)(part + (size_t)sl*2097152 + e);
      s0 += bf2f(u.x & 0xffff); s1 += bf2f(u.x >> 16);
      s2 += bf2f(u.y & 0xffff); s3 += bf2f(u.y >> 16);
    }
    uint2 o;
    o.x = (unsigned)f2bf(PROX(s0)) | ((unsigned)f2bf(PROX(s1)) << 16);
    o.y = (unsigned)f2bf(PROX(s2)) | ((unsigned)f2bf(PROX(s3)) << 16);
    *(uint2*)&Hl[row][c4] = o;
  }
  // ---- phase 2: GEMM ----
  f32x4 acc[4][4];
  #pragma unroll
  for (int a = 0; a < 4; ++a)
    #pragma unroll
    for (int b = 0; b < 4; ++b) acc[a][b] = (f32x4){0,0,0,0};
  for (int it = 0; it < 4; ++it){
    __syncthreads();
    #pragma unroll
    for (int i = 0; i < 8; ++i){
      int o = i*4096 + wave*1024 + lane*16;
      int n = o >> 7, kc = o & 127;
      gl_lds16((const char*)Wbf + (size_t)n*512 + it*128 + kc,
               (char*)&Bl[0][0] + i*4096 + wave*1024);
    }
    __syncthreads();
    #pragma unroll
    for (int h = 0; h < 2; ++h){
      int ko = it*64 + h*32 + q*8;
      s16x8 b[4];
      #pragma unroll
      for (int ni = 0; ni < 4; ++ni) b[ni] = *(const s16x8*)&Bl[wave*64 + ni*16 + r][h*32 + q*8];
      #pragma unroll
      for (int mi = 0; mi < 4; ++mi){
        s16x8 a = *(const s16x8*)&Hl[mi*16 + r][ko];
        #pragma unroll
        for (int ni = 0; ni < 4; ++ni) acc[mi][ni] = mfma16(a, b[ni], acc[mi][ni]);
      }
    }
  }
  // ---- phase 3: LN epilogue ----
  #pragma unroll
  for (int mi = 0; mi < 4; ++mi)
    #pragma unroll
    for (int ii = 0; ii < 4; ++ii){
      float sm = 0.0f, sq = 0.0f;
      #pragma unroll
      for (int ni = 0; ni < 4; ++ni){
        float v = acc[mi][ni][ii];
        sm += v; sq += v*v;
      }
      #pragma unroll
      for (int o = 1; o < 16; o <<= 1){ sm += __shfl_xor(sm, o, 64); sq += __shfl_xor(sq, o, 64); }
      if (r == 0){
        int rl = mi*16 + q*4 + ii;
        SmR[rl][wave] = sm; SqR[rl][wave] = sq;
      }
    }
  __syncthreads();
  float g[4], b[4];
  #pragma unroll
  for (int ni = 0; ni < 4; ++ni){
    g[ni] = gamma[wave*64 + ni*16 + r];
    b[ni] = beta [wave*64 + ni*16 + r];
  }
  #pragma unroll
  for (int mi = 0; mi < 4; ++mi)
    #pragma unroll
    for (int ii = 0; ii < 4; ++ii){
      int rl = mi*16 + q*4 + ii;
      float sm = SmR[rl][0] + SmR[rl][1] + SmR[rl][2] + SmR[rl][3];
      float sq = SqR[rl][0] + SqR[rl][1] + SqR[rl][2] + SqR[rl][3];
      float mean = sm * (1.0f/256.0f);
      float var  = sq * (1.0f/256.0f) - mean*mean;
      float rs   = rsqrtf(var + 1e-5f);
      #pragma unroll
      for (int ni = 0; ni < 4; ++ni){
        out[(size_t)(m0+rl)*256 + wave*64 + ni*16 + r] =
            (acc[mi][ni][ii] - mean)*rs*g[ni] + b[ni];
      }
    }
}

// ===========================================================================
extern "C" void kernel_launch(void* const* d_in, const int* in_sizes, int n_in,
                              void* d_out, int out_size, void* d_ws, size_t ws_size,
                              hipStream_t stream){
  const float* H    = (const float*)d_in[0];
  const float* hops = (const float*)d_in[1];
  const float* Lmat = (const float*)d_in[2];
  const float* U    = (const float*)d_in[3];
  const float* Win  = (const float*)d_in[4];
  const float* gam  = (const float*)d_in[5];
  const float* bet  = (const float*)d_in[6];
  const float* ltau = (const float*)d_in[7];
  float* out = (float*)d_out;

  char* ws = (char*)d_ws;
  float*          Qf   = (float*)(ws + OFF_Q);
  unsigned short* Qt   = (unsigned short*)(ws + OFF_QT);
  unsigned short* Zt   = (unsigned short*)(ws + OFF_ZT);
  float*          Gp   = (float*)(ws + OFF_GP);
  float*          Lm   = (float*)(ws + OFF_LM);
  float*          rdw  = (float*)(ws + OFF_RD);
  float*          Lu   = (float*)(ws + OFF_LU);
  float*          rdu  = (float*)(ws + OFF_RDU);
  float*          re   = (float*)(ws + OFF_RE);
  float*          wv   = (float*)(ws + OFF_W);
  unsigned short* T2w  = (unsigned short*)(ws + OFF_T2);
  unsigned short* hwT  = (unsigned short*)(ws + OFF_HWT);
  unsigned short* Wbf  = (unsigned short*)(ws + OFF_WBF);
  unsigned short* part = (unsigned short*)(ws + OFF_PART);

  hipLaunchKernelGGL(k_pre,    dim3(5),      dim3(256), 0, stream, U, Lu, rdu);
  hipLaunchKernelGGL(k_qsolve, dim3(64,5),   dim3(256), 0, stream, U, Lu, rdu, Qf, Qt);
  hipLaunchKernelGGL(k_zgemm,  dim3(64,5),   dim3(256), 0, stream, hops, Qt, Zt, Gp);
  hipLaunchKernelGGL(k_gred,   dim3(5),      dim3(256), 0, stream, Gp, Lm, rdw, re);
  hipLaunchKernelGGL(k_soft,   dim3(1),      dim3(64),  0, stream, re, ltau, wv, out + 2097152);
  hipLaunchKernelGGL(k_post,   dim3(896),    dim3(256), 0, stream, hops, wv, hwT, Qf, Lm, rdw, T2w, Win, Wbf);
  hipLaunchKernelGGL(k_grad,   dim3(256),    dim3(256), 0, stream, Zt, T2w, part + (size_t)8*2097152);
  hipLaunchKernelGGL(k_big,    dim3(512),    dim3(512), 0, stream, Lmat, hwT, part);
  hipLaunchKernelGGL(k_finln,  dim3(128),    dim3(256), 0, stream, H, part, Wbf, gam, bet, out);
}

// Round 10
// 642.919 us; speedup vs baseline: 1.0109x; 1.0109x over previous
//
#include <hip/hip_runtime.h>
#include <stdint.h>

// ============================================================================
// SubspaceRankHopLayer on MI355X (gfx950)
//
// R6: wave-register chol. 628. R7: reg-staged k_gg 165, no Lbf. 657.
// R9/R10: swizzle fixed conflicts (13.3M->3-4M), neutral. R11: 8-wave split,
// 649. R12: counted-vmcnt depth-2 pipeline: NO CHANGE (165us, MfmaUtil 7.8%,
// HBM 1.1 TB/s). Diagnosis: 3 different schedules all ~165us; per-tile cost
// ~12K cycles vs 320 MFMA => every variant serially exposes HBM latency.
// Mechanism hypothesis: the per-thread A-loads (av) have no dependence on
// the MFMA cluster -> MachineSink sinks them below it, to just before the
// cvt use => vmcnt(4) waits a full ~900cyc latency each tile regardless of
// schedule. (Guide rule #18's sibling hazard.)
// R14 (this round): ONE change — __builtin_amdgcn_sched_barrier(0) after the
// issue block in k_big's main loop, pinning av-loads + B-DMA issue ABOVE the
// MFMA cluster (side-effecting fence also blocks cross-BB sinking).
// Pre-committed read: k_big <=110us => theory confirmed; unchanged => 1.1TB/s
// is a memory-system property -> next: bf16-L prepass under k_post.
// ============================================================================

typedef __attribute__((ext_vector_type(8))) short  s16x8;   // 8 bf16 (4 VGPR)
typedef __attribute__((ext_vector_type(4))) float  f32x4;

#define NNODE 8192
#define DIN   256
#define KHOP  5
#define SDM   64

// ---------------- ws layout (bytes) ----------------
static const size_t OFF_Q    = 0;                                   // Q f32 [5][256][64]
static const size_t OFF_QT   = OFF_Q   + (size_t)5*256*64*4;        // Qt bf16 [5][64][256]
static const size_t OFF_ZT   = OFF_QT  + (size_t)5*64*256*2;        // Zt bf16 [5][8192][64]
static const size_t OFF_GP   = OFF_ZT  + (size_t)5*8192*64*2;       // Gpart f32 [5][64][64][64]
static const size_t OFF_LM   = OFF_GP  + (size_t)5*64*4096*4;       // Lm f32 [5][64][64]
static const size_t OFF_RD   = OFF_LM  + (size_t)5*4096*4;          // rdiag f32 [5][64]
static const size_t OFF_LU   = OFF_RD  + (size_t)5*64*4;            // Lu f32 [5][64][64]
static const size_t OFF_RDU  = OFF_LU  + (size_t)5*4096*4;          // rdiag_u f32 [5][64]
static const size_t OFF_RE   = OFF_RDU + (size_t)5*64*4;            // rank_eff [5] (pad 64)
static const size_t OFF_W    = OFF_RE  + 64;                        // w [5] (pad 64)
static const size_t OFF_T2   = OFF_W   + 64;                        // T2w bf16 [5][256][64]
static const size_t OFF_HWT  = OFF_T2  + (size_t)5*256*64*2;        // hwT bf16 [256][8192]
static const size_t OFF_WBF  = OFF_HWT + (size_t)256*8192*2;        // W_in bf16 [256][256]
static const size_t OFF_HP   = OFF_WBF + (size_t)256*256*2;         // (unused)
static const size_t OFF_PART = OFF_HP  + (size_t)8192*256*2;        // partial bf16 [9][8192][256]

__device__ __forceinline__ unsigned short f2bf(float f){
  unsigned u = __builtin_bit_cast(unsigned, f);
  u += 0x7FFFu + ((u >> 16) & 1u);            // RNE
  return (unsigned short)(u >> 16);
}
__device__ __forceinline__ float bf2f(unsigned h){
  return __builtin_bit_cast(float, h << 16);
}
__device__ __forceinline__ void gl_lds16(const void* g, void* l){
  __builtin_amdgcn_global_load_lds(
      (const __attribute__((address_space(1))) void*)g,
      (__attribute__((address_space(3))) void*)l, 16, 0, 0);
}
__device__ __forceinline__ f32x4 mfma16(s16x8 a, s16x8 b, f32x4 c){
  return __builtin_amdgcn_mfma_f32_16x16x32_bf16(a, b, c, 0, 0, 0);
}
// swizzled byte offset within a chunk row-block: row7 in [0,8), colbyte in [0,128)
__device__ __forceinline__ int swz(int row7, int colbyte){
  return row7*128 + (colbyte ^ (row7 << 4));
}

// ---------------------------------------------------------------------------
// Wave-register Cholesky of 64x64 SPD. One wave; lane = row; a[64] regs.
// ---------------------------------------------------------------------------
__device__ __forceinline__ void wave_chol64(float* a, float& rdk, int lane){
  rdk = 0.0f;
  #pragma unroll
  for (int j = 0; j < 64; ++j){
    float dj  = __shfl(a[j], j);                 // A[j][j] fully updated
    float d   = sqrtf(fmaxf(dj, 1e-20f));
    float rdj = 1.0f / d;
    float cj  = a[j] * rdj;                      // L[i][j] (i>j); d at i==j
    a[j] = cj;
    if (lane == j) rdk = rdj;
    #pragma unroll
    for (int l = j+1; l < 64; ++l)
      a[l] -= cj * __shfl(cj, l);                // rank-1 update, col l
  }
}

// ---------------------------------------------------------------------------
// K_PRE: 5 blocks: Gram (256 thr) + wave0 register-Cholesky of U_k.
// ---------------------------------------------------------------------------
__global__ __launch_bounds__(256) void k_pre(const float* __restrict__ U,
                                             float* __restrict__ Lu,
                                             float* __restrict__ rdu){
  __shared__ float A[64*65];
  int tid = threadIdx.x;
  int k = blockIdx.x;
  const float* Uk = U + (size_t)k*16384;
  int ti = tid >> 4, tj = tid & 15;
  float s[16];
  #pragma unroll
  for (int i = 0; i < 16; ++i) s[i] = 0.0f;
  for (int n = 0; n < 256; ++n){
    f32x4 xa = *(const f32x4*)(Uk + n*64 + ti*4);
    f32x4 xb = *(const f32x4*)(Uk + n*64 + tj*4);
    #pragma unroll
    for (int p = 0; p < 4; ++p)
      #pragma unroll
      for (int q = 0; q < 4; ++q) s[p*4+q] += xa[p]*xb[q];
  }
  #pragma unroll
  for (int p = 0; p < 4; ++p)
    #pragma unroll
    for (int q = 0; q < 4; ++q) A[(ti*4+p)*65 + tj*4+q] = s[p*4+q];
  __syncthreads();
  if (tid < 64){
    int lane = tid;
    float a[64];
    #pragma unroll
    for (int l = 0; l < 64; ++l) a[l] = A[lane*65 + l];
    float rdk;
    wave_chol64(a, rdk, lane);
    #pragma unroll
    for (int l = 0; l < 64; ++l) Lu[(size_t)k*4096 + lane*64 + l] = a[l];
    rdu[k*64 + lane] = rdk;
  }
}

// ---------------------------------------------------------------------------
// K1b: wave-parallel forward solve L x = u_row -> Q rows. grid(64,5).
// ---------------------------------------------------------------------------
__global__ __launch_bounds__(256) void k_qsolve(const float* __restrict__ U,
                                                const float* __restrict__ Lu,
                                                const float* __restrict__ rdu,
                                                float* __restrict__ Qf,
                                                unsigned short* __restrict__ Qt){
  int k = blockIdx.y, tid = threadIdx.x, wave = tid >> 6, lane = tid & 63;
  __shared__ float Al[64*65];
  __shared__ float rds[64];
  for (int e = tid; e < 4096; e += 256) Al[(e>>6)*65 + (e&63)] = Lu[(size_t)k*4096 + e];
  if (tid < 64) rds[tid] = rdu[k*64 + tid];
  __syncthreads();
  int n = blockIdx.x*4 + wave;
  float x = U[((size_t)k*256 + n)*64 + lane];
  #pragma unroll
  for (int j = 0; j < 64; ++j){
    float zj = __shfl(x, j) * rds[j];
    x = (lane == j) ? zj : (lane > j ? x - Al[lane*65+j]*zj : x);
  }
  Qf[((size_t)k*256 + n)*64 + lane] = x;
  Qt[(size_t)k*16384 + lane*256 + n] = f2bf(x);   // Qt[k][s][d]
}

// ---------------------------------------------------------------------------
// K2: Z_k = hops_k @ Q_k [8192,64] bf16 + fused 128-row partial Gram.
// grid(64,5), BM=128 BN=64 BK=64. Gp[(k*64+bx)] = Z_tile^T Z_tile.
// ---------------------------------------------------------------------------
__global__ __launch_bounds__(256,2) void k_zgemm(const float* __restrict__ hops,
                                                 const unsigned short* __restrict__ Qt,
                                                 unsigned short* __restrict__ Zt,
                                                 float* __restrict__ Gp){
  __shared__ __align__(16) unsigned short Al[128][72];
  __shared__ __align__(16) unsigned short Bl[64][64];
  int tid = threadIdx.x, lane = tid & 63, wave = tid >> 6;
  int q = lane >> 4, r = lane & 15;
  int k = blockIdx.y, m0 = blockIdx.x * 128;
  f32x4 acc[2][4];
  #pragma unroll
  for (int a = 0; a < 2; ++a)
    #pragma unroll
    for (int b = 0; b < 4; ++b) acc[a][b] = (f32x4){0,0,0,0};
  int rr = tid >> 1, half = tid & 1;
  for (int it = 0; it < 4; ++it){
    __syncthreads();
    #pragma unroll
    for (int i = 0; i < 2; ++i){
      int o = i*4096 + wave*1024 + lane*16;
      int srow = o >> 7, kc = (o & 127) >> 1;
      gl_lds16(Qt + (size_t)k*16384 + srow*256 + it*64 + kc,
               (char*)&Bl[0][0] + i*4096 + wave*1024);
    }
    const float* ga = hops + ((size_t)k*NNODE + m0 + rr)*256 + it*64 + half*32;
    f32x4 v[8];
    #pragma unroll
    for (int i = 0; i < 8; ++i) v[i] = *(const f32x4*)(ga + i*4);
    #pragma unroll
    for (int i = 0; i < 4; ++i){
      s16x8 t;
      #pragma unroll
      for (int j = 0; j < 8; ++j){ int e = i*8+j; t[j] = (short)f2bf(v[e>>2][e&3]); }
      *(s16x8*)&Al[rr][half*32 + i*8] = t;
    }
    __syncthreads();
    #pragma unroll
    for (int h = 0; h < 2; ++h){
      int ko = h*32 + q*8;
      s16x8 b[4];
      #pragma unroll
      for (int ni = 0; ni < 4; ++ni) b[ni] = *(const s16x8*)&Bl[ni*16 + r][ko];
      #pragma unroll
      for (int mi = 0; mi < 2; ++mi){
        s16x8 a = *(const s16x8*)&Al[wave*32 + mi*16 + r][ko];
        #pragma unroll
        for (int ni = 0; ni < 4; ++ni) acc[mi][ni] = mfma16(a, b[ni], acc[mi][ni]);
      }
    }
  }
  // epilogue: write Zt (global) + stage Z bf16 into Al (own wave's rows only)
  #pragma unroll
  for (int mi = 0; mi < 2; ++mi)
    #pragma unroll
    for (int ni = 0; ni < 4; ++ni)
      #pragma unroll
      for (int ii = 0; ii < 4; ++ii){
        int ml = wave*32 + mi*16 + q*4 + ii;
        int sc = ni*16 + r;
        unsigned short v = f2bf(acc[mi][ni][ii]);
        Zt[((size_t)k*NNODE + m0 + ml)*64 + sc] = v;
        Al[ml][sc] = v;
      }
  __syncthreads();
  // partial Gram of this 128-row tile (gpart's loop, pitch 72)
  int ti = tid >> 4, tj = tid & 15;
  float g16[16];
  #pragma unroll
  for (int i = 0; i < 16; ++i) g16[i] = 0.0f;
  for (int n = 0; n < 128; ++n){
    const unsigned short* row = &Al[n][0];
    uint2 ua = *(const uint2*)(row + ti*4);
    uint2 ub = *(const uint2*)(row + tj*4);
    float xa[4] = { bf2f(ua.x & 0xffff), bf2f(ua.x >> 16), bf2f(ua.y & 0xffff), bf2f(ua.y >> 16) };
    float xb[4] = { bf2f(ub.x & 0xffff), bf2f(ub.x >> 16), bf2f(ub.y & 0xffff), bf2f(ub.y >> 16) };
    #pragma unroll
    for (int p = 0; p < 4; ++p)
      #pragma unroll
      for (int qn = 0; qn < 4; ++qn) g16[p*4+qn] += xa[p]*xb[qn];
  }
  float* go = Gp + ((size_t)(k*64 + blockIdx.x))*4096;
  #pragma unroll
  for (int p = 0; p < 4; ++p)
    #pragma unroll
    for (int qn = 0; qn < 4; ++qn) go[(ti*4+p)*64 + tj*4+qn] = g16[p*4+qn];
}

// ---------------------------------------------------------------------------
// K4: reduce 64 Gpart chunks -> G; rank_eff; M = I + coeff*G; register-chol.
// ---------------------------------------------------------------------------
__global__ __launch_bounds__(256) void k_gred(const float* __restrict__ Gp,
                                              float* __restrict__ LmO,
                                              float* __restrict__ rdO,
                                              float* __restrict__ reO){
  int k = blockIdx.x, tid = threadIdx.x;
  __shared__ float A[64*65];
  __shared__ float red[256];
  int ti = tid >> 4, tj = tid & 15;
  float s[16];
  #pragma unroll
  for (int i = 0; i < 16; ++i) s[i] = 0.0f;
  for (int c = 0; c < 64; ++c){
    const float* g = Gp + ((size_t)(k*64 + c))*4096 + (ti*4)*64 + tj*4;
    #pragma unroll
    for (int p = 0; p < 4; ++p)
      #pragma unroll
      for (int qn = 0; qn < 4; ++qn) s[p*4+qn] += g[p*64+qn];
  }
  const float sc    = 1.0f / (8192.0f + 1e-8f);
  const float coeff = 64.0f / (8192.0f*0.25f + 1e-8f);
  float trp = 0.0f, tr2p = 0.0f;
  #pragma unroll
  for (int p = 0; p < 4; ++p)
    #pragma unroll
    for (int qn = 0; qn < 4; ++qn){
      float gg = s[p*4+qn];
      float sg = gg * sc;
      tr2p += sg*sg;
      int row = ti*4+p, col = tj*4+qn;
      if (row == col) trp += sg;
      A[row*65 + col] = (row == col ? 1.0f : 0.0f) + coeff*gg;
    }
  red[tid] = trp; __syncthreads();
  for (int o = 128; o > 0; o >>= 1){ if (tid < o) red[tid] += red[tid+o]; __syncthreads(); }
  float tr = red[0]; __syncthreads();
  red[tid] = tr2p; __syncthreads();
  for (int o = 128; o > 0; o >>= 1){ if (tid < o) red[tid] += red[tid+o]; __syncthreads(); }
  float tr2 = red[0];
  if (tid == 0) reO[k] = tr*tr / (tr2 + 1e-8f);
  __syncthreads();
  if (tid < 64){
    int lane = tid;
    float a[64];
    #pragma unroll
    for (int l = 0; l < 64; ++l) a[l] = A[lane*65 + l];
    float rdk;
    wave_chol64(a, rdk, lane);
    #pragma unroll
    for (int l = 0; l < 64; ++l) LmO[(size_t)k*4096 + lane*64 + l] = a[l];
    rdO[k*64 + lane] = rdk;
  }
}

// ---------------------------------------------------------------------------
// K5: tau, softmax over rank_effs -> w; write output tail. 1 block.
// ---------------------------------------------------------------------------
__global__ void k_soft(const float* __restrict__ re, const float* __restrict__ ltau,
                       float* __restrict__ wv, float* __restrict__ dtail){
  if (threadIdx.x == 0){
    float tau = expf(ltau[0]);
    tau = fminf(fmaxf(tau, 0.1f), 10.0f);
    float r[5], m = -1e30f;
    for (int i = 0; i < 5; ++i){ r[i] = re[i]; m = fmaxf(m, r[i]); }
    float e[5], sum = 0.0f;
    for (int i = 0; i < 5; ++i){ e[i] = expf((r[i]-m)/tau); sum += e[i]; }
    for (int i = 0; i < 5; ++i){
      float w = e[i]/sum;
      wv[i] = w; dtail[i] = r[i]; dtail[5+i] = w;
    }
  }
}

// ---------------------------------------------------------------------------
// K_POST: horizontal fusion, 896 blocks:
//   [0,512):   hwT role; [512,832): t2w role; [832,896): wbf role
// ---------------------------------------------------------------------------
__global__ __launch_bounds__(256) void k_post(const float* __restrict__ hops,
                                              const float* __restrict__ wv,
                                              unsigned short* __restrict__ hwT,
                                              const float* __restrict__ Qf,
                                              const float* __restrict__ LmI,
                                              const float* __restrict__ rdI,
                                              unsigned short* __restrict__ T2w,
                                              const float* __restrict__ Win,
                                              unsigned short* __restrict__ Wbf){
  __shared__ float T[64*65];
  __shared__ float rds[64];
  int bid = blockIdx.x, tid = threadIdx.x;
  if (bid < 512){
    // ---- hwT role ----
    int n0 = (bid & 127)*64, d0 = (bid >> 7)*64;
    float wl[5];
    #pragma unroll
    for (int k = 0; k < 5; ++k) wl[k] = -0.15f * wv[k];   // -ETA*LAM_LAP*w_k
    for (int e = tid; e < 1024; e += 256){
      int row = e >> 4, c4 = (e & 15)*4;
      f32x4 acc = (f32x4){0,0,0,0};
      #pragma unroll
      for (int k = 0; k < 5; ++k){
        f32x4 v = *(const f32x4*)(hops + ((size_t)k*NNODE + n0 + row)*256 + d0 + c4);
        acc += v * wl[k];
      }
      T[row*65 + c4+0] = acc[0]; T[row*65 + c4+1] = acc[1];
      T[row*65 + c4+2] = acc[2]; T[row*65 + c4+3] = acc[3];
    }
    __syncthreads();
    for (int e = tid; e < 1024; e += 256){
      int dr = e >> 4, c4 = (e & 15)*4;
      unsigned short h0 = f2bf(T[(c4+0)*65 + dr]);
      unsigned short h1 = f2bf(T[(c4+1)*65 + dr]);
      unsigned short h2 = f2bf(T[(c4+2)*65 + dr]);
      unsigned short h3 = f2bf(T[(c4+3)*65 + dr]);
      uint2 u; u.x = (unsigned)h0 | ((unsigned)h1 << 16); u.y = (unsigned)h2 | ((unsigned)h3 << 16);
      *(uint2*)(hwT + (size_t)(d0+dr)*NNODE + n0 + c4) = u;
    }
  } else if (bid < 832){
    // ---- t2w role ----
    int i = bid - 512;
    int k = i >> 6, xb = i & 63;
    int wave = tid >> 6, lane = tid & 63;
    for (int e = tid; e < 4096; e += 256) T[(e>>6)*65 + (e&63)] = LmI[(size_t)k*4096 + e];
    if (tid < 64) rds[tid] = rdI[k*64 + tid];
    __syncthreads();
    int n = xb*4 + wave;
    float x = Qf[((size_t)k*256 + n)*64 + lane];
    #pragma unroll
    for (int j = 0; j < 64; ++j){                 // forward: L z = q
      float zj = __shfl(x, j) * rds[j];
      x = (lane == j) ? zj : (lane > j ? x - T[lane*65+j]*zj : x);
    }
    #pragma unroll
    for (int j = 63; j >= 0; --j){                // backward: L^T y = z
      float yj = __shfl(x, j) * rds[j];
      x = (lane == j) ? yj : (lane < j ? x - T[j*65+lane]*yj : x);
    }
    float scale = 0.5f * wv[k];                   // ETA * w_k
    T2w[((size_t)k*256 + n)*64 + lane] = f2bf(scale * x);
  } else {
    // ---- wbf role ----
    int i = bid - 832;
    int e = (i*256 + tid)*4;
    f32x4 v = *(const f32x4*)(Win + e);
    uint2 u;
    u.x = (unsigned)f2bf(v[0]) | ((unsigned)f2bf(v[1]) << 16);
    u.y = (unsigned)f2bf(v[2]) | ((unsigned)f2bf(v[3]) << 16);
    *(uint2*)(Wbf + e) = u;
  }
}

// ---------------------------------------------------------------------------
// K_GRAD: gradgemm standalone. 256 blocks x 256 thr, 36,864 B LDS.
// Zstack[8192,320] @ T2w-stack[320,256] -> slab 8. Both-sides XOR swizzle.
// ---------------------------------------------------------------------------
__global__ __launch_bounds__(256,2) void k_grad(const unsigned short* __restrict__ Zt,
                                                const unsigned short* __restrict__ T2w,
                                                unsigned short* __restrict__ out8){
  __shared__ __align__(16) unsigned short SM[18432];   // 36,864 B
  char* Al = (char*)SM;               // 4 chunks x 1024 B (32 rows x 64)
  char* Bl = (char*)SM + 4096;        // 32 chunks x 1024 B (256 rows x 64)
  int tid = threadIdx.x, lane = tid & 63, wave = tid >> 6;
  int q = lane >> 4, r = lane & 15;
  int m0 = blockIdx.x * 32;
  int gr8 = lane >> 3;                        // row-in-chunk
  int gcS = ((lane & 7) ^ gr8) * 16;          // pre-swizzled src byte col
  f32x4 acc[2][4];
  #pragma unroll
  for (int a = 0; a < 2; ++a)
    #pragma unroll
    for (int b = 0; b < 4; ++b) acc[a][b] = (f32x4){0,0,0,0};
  for (int kk = 0; kk < 5; ++kk){
    __syncthreads();
    {
      int grow = wave*8 + gr8;                // A chunk = wave
      gl_lds16((const char*)Zt + ((size_t)kk*NNODE + m0 + grow)*128 + gcS,
               Al + wave*1024);
    }
    #pragma unroll
    for (int i = 0; i < 8; ++i){
      int cb = i*4 + wave;                    // chunk 0..31
      int grow = cb*8 + gr8;
      gl_lds16((const char*)T2w + (size_t)kk*32768 + (size_t)grow*128 + gcS,
               Bl + cb*1024);
    }
    __syncthreads();
    #pragma unroll
    for (int h = 0; h < 2; ++h){
      int kb = h*64 + q*16;   // byte col
      s16x8 b[4];
      #pragma unroll
      for (int ni = 0; ni < 4; ++ni){
        int row = wave*64 + ni*16 + r;
        b[ni] = *(const s16x8*)(Bl + (row>>3)*1024 + swz(row&7, kb));
      }
      #pragma unroll
      for (int mi = 0; mi < 2; ++mi){
        int row = mi*16 + r;
        s16x8 a = *(const s16x8*)(Al + (row>>3)*1024 + swz(row&7, kb));
        #pragma unroll
        for (int ni = 0; ni < 4; ++ni) acc[mi][ni] = mfma16(a, b[ni], acc[mi][ni]);
      }
    }
  }
  #pragma unroll
  for (int mi = 0; mi < 2; ++mi)
    #pragma unroll
    for (int ni = 0; ni < 4; ++ni)
      #pragma unroll
      for (int ii = 0; ii < 4; ++ii){
        int m = m0 + mi*16 + q*4 + ii;
        int n = wave*64 + ni*16 + r;
        out8[(size_t)m*256 + n] = f2bf(acc[mi][ni][ii]);
      }
}

// ---------------------------------------------------------------------------
// K_BIG: 512 blocks x 512 thr (8 waves), 1 block/CU. Depth-2 counted-vmcnt
// pipeline, 3 LDS buffers. R14: sched_barrier(0) AFTER the issue block pins
// av-loads + B-DMA issue above the MFMA cluster (blocks MachineSink).
// ---------------------------------------------------------------------------
__global__ __launch_bounds__(512,2) void k_big(const float* __restrict__ Lf,
                                               const unsigned short* __restrict__ Bt,
                                               unsigned short* __restrict__ part){
  __shared__ __align__(16) unsigned short SM[74880];   // 149,760 B = 3 bufs
  char* SMb = (char*)SM;
  const int CH48 = 48*1040;            // one buffer (16 A + 32 B chunks)
  const int BOFF = 16*1040;            // B region offset within a buffer
  int tid = threadIdx.x, lane = tid & 63, wave = tid >> 6;   // 8 waves
  int q = lane >> 4, r = lane & 15;
  int wr = wave >> 2, wc = wave & 3;
  int m0 = (blockIdx.x & 63) * 128;
  int by = blockIdx.x >> 6;
  size_t kbase = (size_t)by * 1024;
  int sr = lane >> 3;                       // row-in-chunk
  int scS  = ((lane & 7) ^ sr) * 8;         // B: pre-swizzled global col (shorts)
  int sc8a = (lane & 7) * 8;                // A: global col (f32 elems)
  int adst = swz(sr, (lane & 7) * 16);      // A: swizzled dest byte in chunk
  f32x4 acc[4][4];
  #pragma unroll
  for (int a = 0; a < 4; ++a)
    #pragma unroll
    for (int b = 0; b < 4; ++b) acc[a][b] = (f32x4){0,0,0,0};
  f32x4 av[2][2];
  // ---- prologue: stage tiles 0 and 1 ----
  {
    f32x4 av0[2][2];
    #pragma unroll
    for (int i = 0; i < 2; ++i){               // A0 regs (4 loads)
      int c = wave*2 + i;
      const float* p = Lf + (size_t)(m0 + c*8 + sr)*NNODE + kbase + sc8a;
      av0[i][0] = *(const f32x4*)p;
      av0[i][1] = *(const f32x4*)(p + 4);
    }
    #pragma unroll
    for (int i = 0; i < 4; ++i){               // B0 dma (4)
      int cb = wave*4 + i;
      gl_lds16(Bt + (size_t)(cb*8 + sr)*NNODE + kbase + scS,
               SMb + 0*CH48 + BOFF + cb*1040);
    }
    #pragma unroll
    for (int i = 0; i < 2; ++i){               // A1 regs (4)
      int c = wave*2 + i;
      const float* p = Lf + (size_t)(m0 + c*8 + sr)*NNODE + (kbase + 64) + sc8a;
      av[i][0] = *(const f32x4*)p;
      av[i][1] = *(const f32x4*)(p + 4);
    }
    #pragma unroll
    for (int i = 0; i < 4; ++i){               // B1 dma (4)
      int cb = wave*4 + i;
      gl_lds16(Bt + (size_t)(cb*8 + sr)*NNODE + (kbase + 64) + scS,
               SMb + 1*CH48 + BOFF + cb*1040);
    }
    // A0 done after 12 remain (B0,A1,B1)
    asm volatile("s_waitcnt vmcnt(12)" ::: "memory");
    __builtin_amdgcn_sched_barrier(0);
    #pragma unroll
    for (int i = 0; i < 2; ++i){
      int c = wave*2 + i;
      s16x8 t;
      #pragma unroll
      for (int e = 0; e < 8; ++e) t[e] = (short)f2bf(av0[i][e>>2][e&3]);
      *(s16x8*)(SMb + 0*CH48 + c*1040 + adst) = t;
    }
    // B0 + A1 done after 4 remain (B1)
    asm volatile("s_waitcnt vmcnt(4)" ::: "memory");
    __builtin_amdgcn_sched_barrier(0);
    #pragma unroll
    for (int i = 0; i < 2; ++i){
      int c = wave*2 + i;
      s16x8 t;
      #pragma unroll
      for (int e = 0; e < 8; ++e) t[e] = (short)f2bf(av[i][e>>2][e&3]);
      *(s16x8*)(SMb + 1*CH48 + c*1040 + adst) = t;
    }
    asm volatile("s_waitcnt lgkmcnt(0)" ::: "memory");
    __builtin_amdgcn_sched_barrier(0);
    __builtin_amdgcn_s_barrier();
  }
  // ---- main loop ----
  for (int t = 0; t < 16; ++t){
    char* cbuf = SMb + (t % 3)*CH48;
    char* nbuf = SMb + ((t + 2) % 3)*CH48;
    if (t < 14){
      size_t k2 = kbase + (size_t)(t+2)*64;
      #pragma unroll
      for (int i = 0; i < 2; ++i){             // A(t+2) regs
        int c = wave*2 + i;
        const float* p = Lf + (size_t)(m0 + c*8 + sr)*NNODE + k2 + sc8a;
        av[i][0] = *(const f32x4*)p;
        av[i][1] = *(const f32x4*)(p + 4);
      }
      #pragma unroll
      for (int i = 0; i < 4; ++i){             // B(t+2) dma
        int cb = wave*4 + i;
        gl_lds16(Bt + (size_t)(cb*8 + sr)*NNODE + k2 + scS,
                 nbuf + BOFF + cb*1040);
      }
    }
    // R14: pin the issue block ABOVE the MFMA cluster (blocks MachineSink
    // from dragging the av loads down to their cvt use after vmcnt(4)).
    __builtin_amdgcn_sched_barrier(0);
    // MFMA from cbuf (swizzled fragment reads)
    #pragma unroll
    for (int h = 0; h < 2; ++h){
      int kb = h*64 + q*16;   // byte col
      s16x8 b[4];
      #pragma unroll
      for (int ni = 0; ni < 4; ++ni){
        int d = wc*64 + ni*16 + r;
        b[ni] = *(const s16x8*)(cbuf + BOFF + (d>>3)*1040 + swz(d&7, kb));
      }
      #pragma unroll
      for (int mi = 0; mi < 4; ++mi){
        int m = wr*64 + mi*16 + r;
        s16x8 a = *(const s16x8*)(cbuf + (m>>3)*1040 + swz(m&7, kb));
        #pragma unroll
        for (int ni = 0; ni < 4; ++ni) acc[mi][ni] = mfma16(a, b[ni], acc[mi][ni]);
      }
    }
    if (t < 14){
      // retires B(t+1) (4) + A(t+2) (4); leaves B(t+2) (4) in flight
      asm volatile("s_waitcnt vmcnt(4)" ::: "memory");
      __builtin_amdgcn_sched_barrier(0);
      #pragma unroll
      for (int i = 0; i < 2; ++i){
        int c = wave*2 + i;
        s16x8 tt;
        #pragma unroll
        for (int e = 0; e < 8; ++e) tt[e] = (short)f2bf(av[i][e>>2][e&3]);
        *(s16x8*)(nbuf + c*1040 + adst) = tt;
      }
      asm volatile("s_waitcnt lgkmcnt(0)" ::: "memory");
      __builtin_amdgcn_sched_barrier(0);
    } else if (t == 14){
      // drain B(15) before its consumption at t=15
      asm volatile("s_waitcnt vmcnt(0) lgkmcnt(0)" ::: "memory");
      __builtin_amdgcn_sched_barrier(0);
    }
    if (t < 15) __builtin_amdgcn_s_barrier();
  }
  unsigned short* o = part + (size_t)by * 2097152;
  #pragma unroll
  for (int mi = 0; mi < 4; ++mi)
    #pragma unroll
    for (int ni = 0; ni < 4; ++ni)
      #pragma unroll
      for (int ii = 0; ii < 4; ++ii){
        int m = m0 + wr*64 + mi*16 + q*4 + ii;
        int n = wc*64 + ni*16 + r;
        o[(size_t)m*256 + n] = f2bf(acc[mi][ni][ii]);
      }
}

// ---------------------------------------------------------------------------
// K_FINLN: fused combine + GEMM + LayerNorm. grid(128), BM=64 BN=256 K=256.
// ---------------------------------------------------------------------------
__global__ __launch_bounds__(256,2) void k_finln(const float* __restrict__ H,
                                                 const unsigned short* __restrict__ part,
                                                 const unsigned short* __restrict__ Wbf,
                                                 const float* __restrict__ gamma,
                                                 const float* __restrict__ beta,
                                                 float* __restrict__ out){
  __shared__ __align__(16) unsigned short Hl[64][264];   // padded: +4 banks/row
  __shared__ __align__(16) unsigned short Bl[256][64];
  __shared__ float SmR[64][4];
  __shared__ float SqR[64][4];
  int tid = threadIdx.x, lane = tid & 63, wave = tid >> 6;
  int q = lane >> 4, r = lane & 15;
  int m0 = blockIdx.x * 64;
  // ---- phase 1: build Hprox tile ----
  #define PROX(a) ({ float _t = fabsf(a) - 0.025f; _t > 0.0f ? copysignf(_t,(a)) : 0.0f; })
  for (int g = tid; g < 4096; g += 256){
    int row = g >> 6, c4 = (g & 63) * 4;
    size_t e = (size_t)(m0 + row)*256 + c4;
    f32x4 h = *(const f32x4*)(H + e);
    float s0 = h[0], s1 = h[1], s2 = h[2], s3 = h[3];
    #pragma unroll
    for (int sl = 0; sl < 9; ++sl){
      uint2 u = *(const uint2*)(part + (size_t)sl*2097152 + e);
      s0 += bf2f(u.x & 0xffff); s1 += bf2f(u.x >> 16);
      s2 += bf2f(u.y & 0xffff); s3 += bf2f(u.y >> 16);
    }
    uint2 o;
    o.x = (unsigned)f2bf(PROX(s0)) | ((unsigned)f2bf(PROX(s1)) << 16);
    o.y = (unsigned)f2bf(PROX(s2)) | ((unsigned)f2bf(PROX(s3)) << 16);
    *(uint2*)&Hl[row][c4] = o;
  }
  // ---- phase 2: GEMM ----
  f32x4 acc[4][4];
  #pragma unroll
  for (int a = 0; a < 4; ++a)
    #pragma unroll
    for (int b = 0; b < 4; ++b) acc[a][b] = (f32x4){0,0,0,0};
  for (int it = 0; it < 4; ++it){
    __syncthreads();
    #pragma unroll
    for (int i = 0; i < 8; ++i){
      int o = i*4096 + wave*1024 + lane*16;
      int n = o >> 7, kc = o & 127;
      gl_lds16((const char*)Wbf + (size_t)n*512 + it*128 + kc,
               (char*)&Bl[0][0] + i*4096 + wave*1024);
    }
    __syncthreads();
    #pragma unroll
    for (int h = 0; h < 2; ++h){
      int ko = it*64 + h*32 + q*8;
      s16x8 b[4];
      #pragma unroll
      for (int ni = 0; ni < 4; ++ni) b[ni] = *(const s16x8*)&Bl[wave*64 + ni*16 + r][h*32 + q*8];
      #pragma unroll
      for (int mi = 0; mi < 4; ++mi){
        s16x8 a = *(const s16x8*)&Hl[mi*16 + r][ko];
        #pragma unroll
        for (int ni = 0; ni < 4; ++ni) acc[mi][ni] = mfma16(a, b[ni], acc[mi][ni]);
      }
    }
  }
  // ---- phase 3: LN epilogue ----
  #pragma unroll
  for (int mi = 0; mi < 4; ++mi)
    #pragma unroll
    for (int ii = 0; ii < 4; ++ii){
      float sm = 0.0f, sq = 0.0f;
      #pragma unroll
      for (int ni = 0; ni < 4; ++ni){
        float v = acc[mi][ni][ii];
        sm += v; sq += v*v;
      }
      #pragma unroll
      for (int o = 1; o < 16; o <<= 1){ sm += __shfl_xor(sm, o, 64); sq += __shfl_xor(sq, o, 64); }
      if (r == 0){
        int rl = mi*16 + q*4 + ii;
        SmR[rl][wave] = sm; SqR[rl][wave] = sq;
      }
    }
  __syncthreads();
  float g[4], b[4];
  #pragma unroll
  for (int ni = 0; ni < 4; ++ni){
    g[ni] = gamma[wave*64 + ni*16 + r];
    b[ni] = beta [wave*64 + ni*16 + r];
  }
  #pragma unroll
  for (int mi = 0; mi < 4; ++mi)
    #pragma unroll
    for (int ii = 0; ii < 4; ++ii){
      int rl = mi*16 + q*4 + ii;
      float sm = SmR[rl][0] + SmR[rl][1] + SmR[rl][2] + SmR[rl][3];
      float sq = SqR[rl][0] + SqR[rl][1] + SqR[rl][2] + SqR[rl][3];
      float mean = sm * (1.0f/256.0f);
      float var  = sq * (1.0f/256.0f) - mean*mean;
      float rs   = rsqrtf(var + 1e-5f);
      #pragma unroll
      for (int ni = 0; ni < 4; ++ni){
        out[(size_t)(m0+rl)*256 + wave*64 + ni*16 + r] =
            (acc[mi][ni][ii] - mean)*rs*g[ni] + b[ni];
      }
    }
}

// ===========================================================================
extern "C" void kernel_launch(void* const* d_in, const int* in_sizes, int n_in,
                              void* d_out, int out_size, void* d_ws, size_t ws_size,
                              hipStream_t stream){
  const float* H    = (const float*)d_in[0];
  const float* hops = (const float*)d_in[1];
  const float* Lmat = (const float*)d_in[2];
  const float* U    = (const float*)d_in[3];
  const float* Win  = (const float*)d_in[4];
  const float* gam  = (const float*)d_in[5];
  const float* bet  = (const float*)d_in[6];
  const float* ltau = (const float*)d_in[7];
  float* out = (float*)d_out;

  char* ws = (char*)d_ws;
  float*          Qf   = (float*)(ws + OFF_Q);
  unsigned short* Qt   = (unsigned short*)(ws + OFF_QT);
  unsigned short* Zt   = (unsigned short*)(ws + OFF_ZT);
  float*          Gp   = (float*)(ws + OFF_GP);
  float*          Lm   = (float*)(ws + OFF_LM);
  float*          rdw  = (float*)(ws + OFF_RD);
  float*          Lu   = (float*)(ws + OFF_LU);
  float*          rdu  = (float*)(ws + OFF_RDU);
  float*          re   = (float*)(ws + OFF_RE);
  float*          wv   = (float*)(ws + OFF_W);
  unsigned short* T2w  = (unsigned short*)(ws + OFF_T2);
  unsigned short* hwT  = (unsigned short*)(ws + OFF_HWT);
  unsigned short* Wbf  = (unsigned short*)(ws + OFF_WBF);
  unsigned short* part = (unsigned short*)(ws + OFF_PART);

  hipLaunchKernelGGL(k_pre,    dim3(5),      dim3(256), 0, stream, U, Lu, rdu);
  hipLaunchKernelGGL(k_qsolve, dim3(64,5),   dim3(256), 0, stream, U, Lu, rdu, Qf, Qt);
  hipLaunchKernelGGL(k_zgemm,  dim3(64,5),   dim3(256), 0, stream, hops, Qt, Zt, Gp);
  hipLaunchKernelGGL(k_gred,   dim3(5),      dim3(256), 0, stream, Gp, Lm, rdw, re);
  hipLaunchKernelGGL(k_soft,   dim3(1),      dim3(64),  0, stream, re, ltau, wv, out + 2097152);
  hipLaunchKernelGGL(k_post,   dim3(896),    dim3(256), 0, stream, hops, wv, hwT, Qf, Lm, rdw, T2w, Win, Wbf);
  hipLaunchKernelGGL(k_grad,   dim3(256),    dim3(256), 0, stream, Zt, T2w, part + (size_t)8*2097152);
  hipLaunchKernelGGL(k_big,    dim3(512),    dim3(512), 0, stream, Lmat, hwT, part);
  hipLaunchKernelGGL(k_finln,  dim3(128),    dim3(256), 0, stream, H, part, Wbf, gam, bet, out);
}